// Round 8
// baseline (742.268 us; speedup 1.0000x reference)
//
#include <hip/hip_runtime.h>
#include <hip/hip_cooperative_groups.h>

namespace cg = cooperative_groups;

#define NNODES 100000
#define NEDGES 625000
#define DFEAT  128
#define NGRAPH 256
#define DOUTC  10

#define NBLK   256
#define NTHR   512
#define NTHREADS (NBLK * NTHR)          // 131072
#define NWAVES   (NTHREADS / 64)        // 2048
#define NGROUPS  (NTHREADS / 16)        // 8192
#define NCHUNK   ((NNODES + 1023) / 1024)   // 98 scan chunks

typedef __attribute__((ext_vector_type(8))) short bf16x8;
typedef __attribute__((ext_vector_type(4))) float f32x4;
typedef __attribute__((ext_vector_type(8))) ushort ushort8v;

__device__ __forceinline__ ushort f2bf(float f) {
    __bf16 b = (__bf16)f;
    return __builtin_bit_cast(ushort, b);
}
__device__ __forceinline__ float bf2f(ushort u) {
    return __builtin_bit_cast(float, (uint)u << 16);
}

struct Params {
    const float* x;
    const int*   rows;
    const int*   cols;
    const int*   batch;
    const float* W[6];        // W1_0, W2_0, W1_1, W2_1, W1_2, W2_2
    const float* Wc;
    const float* bc;
    float*       out;
    ushort*      Hb;
    ushort*      Hc;
    ushort*      Ab;
    ushort*      Wb;
    float*       gsum;
    int*         deg;
    int*         offs;
    int*         cursor;
    int*         scol;
    int*         bsum;
    int*         bbase;
};

__global__ __launch_bounds__(NTHR, 2) void gnn_mega(Params p) {
    cg::grid_group grid = cg::this_grid();
    const int tid  = blockIdx.x * NTHR + threadIdx.x;
    const int t    = threadIdx.x;
    const int b    = blockIdx.x;

    __shared__ int  shi[NTHR];
    __shared__ int  shb[128];
    __shared__ float red[128];
    __shared__ int  bounds[2];

    // ---------------- P0: zero deg/gsum, convert weights + x -------------
    if (tid < NNODES) p.deg[tid] = 0;
    if (tid < NGRAPH * DFEAT) p.gsum[tid] = 0.f;
    {   // weights: 6 * 16384 = 98304 elems, one pass
        if (tid < 6 * DFEAT * DFEAT) {
            int m = tid >> 14, j = tid & 16383;
            p.Wb[tid] = f2bf(p.W[m][j]);
        }
        // x: 1.6M chunks of 8 floats
        const int n8 = NNODES * DFEAT / 8;
        for (int i = tid; i < n8; i += NTHREADS) {
            float4 a = *(const float4*)&p.x[(size_t)i * 8];
            float4 c = *(const float4*)&p.x[(size_t)i * 8 + 4];
            ushort8v o;
            o[0] = f2bf(a.x); o[1] = f2bf(a.y); o[2] = f2bf(a.z); o[3] = f2bf(a.w);
            o[4] = f2bf(c.x); o[5] = f2bf(c.y); o[6] = f2bf(c.z); o[7] = f2bf(c.w);
            *(ushort8v*)&p.Hb[(size_t)i * 8] = o;
        }
    }
    grid.sync();

    // ---------------- P1: degree histogram -------------------------------
    for (int i = tid; i < NEDGES; i += NTHREADS)
        atomicAdd(&p.deg[p.rows[i]], 1);
    grid.sync();

    // ---------------- P2a: per-chunk sums ---------------------------------
    if (b < NCHUNK) {
        int i0 = b * 1024 + t * 2;
        int v0 = (i0 < NNODES) ? p.deg[i0] : 0;
        int v1 = (i0 + 1 < NNODES) ? p.deg[i0 + 1] : 0;
        shi[t] = v0 + v1;
        __syncthreads();
        for (int off = 256; off > 0; off >>= 1) {
            if (t < off) shi[t] += shi[t + off];
            __syncthreads();
        }
        if (t == 0) p.bsum[b] = shi[0];
    }
    grid.sync();

    // ---------------- P2b: scan chunk sums (block 0) ----------------------
    if (b == 0) {
        if (t < 128) shb[t] = (t < NCHUNK) ? p.bsum[t] : 0;
        __syncthreads();
        if (t == 0) {
            int run = 0;
            for (int i = 0; i < NCHUNK; ++i) { int v = shb[i]; shb[i] = run; run += v; }
        }
        __syncthreads();
        if (t < NCHUNK) p.bbase[t] = shb[t];
    }
    grid.sync();

    // ---------------- P2c: write offs + cursor ----------------------------
    if (b < NCHUNK) {
        int i0 = b * 1024 + t * 2;
        int v0 = (i0 < NNODES) ? p.deg[i0] : 0;
        int v1 = (i0 + 1 < NNODES) ? p.deg[i0 + 1] : 0;
        int s = v0 + v1;
        shi[t] = s;
        __syncthreads();
        int x = s;
        for (int off = 1; off < NTHR; off <<= 1) {
            int y = (t >= off) ? shi[t - off] : 0;
            __syncthreads();
            x += y;
            shi[t] = x;
            __syncthreads();
        }
        int pre = p.bbase[b] + x - s;
        if (i0 < NNODES)     { p.offs[i0] = pre;     p.cursor[i0] = pre; }
        if (i0 + 1 < NNODES) { p.offs[i0 + 1] = pre + v0; p.cursor[i0 + 1] = pre + v0; }
    }
    if (tid == 0) p.offs[NNODES] = NEDGES;
    grid.sync();

    // ---------------- P3: scatter edges -----------------------------------
    for (int i = tid; i < NEDGES; i += NTHREADS) {
        int pos = atomicAdd(&p.cursor[p.rows[i]], 1);
        p.scol[pos] = p.cols[i];
    }
    grid.sync();

    // ---------------- P4: three GNN layers --------------------------------
    const ushort* hcur = p.Hb;
    ushort* hnext = p.Hc;
    const int gidx = tid >> 4;            // 16-lane group id
    const int gl   = t & 15;
    const int lane = t & 63;
    const int l15  = lane & 15, lhi = lane >> 4;
    const int gw   = tid >> 6;            // global wave id
    const int half = gw & 1;
    const int team = gw >> 1;             // 1024 teams

    for (int l = 0; l < 3; ++l) {
        // --- aggregate: A[n] = sum H[scol[e]], 16-lane group per node ---
        for (int node = gidx; node < NNODES; node += NGROUPS) {
            int beg = p.offs[node];
            int end = p.offs[node + 1];
            float a[8] = {};
            int e = beg;
            for (; e + 2 <= end; e += 2) {
                int c0 = p.scol[e];
                int c1 = p.scol[e + 1];
                ushort8v v0 = *(const ushort8v*)&hcur[(size_t)c0 * DFEAT + gl * 8];
                ushort8v v1 = *(const ushort8v*)&hcur[(size_t)c1 * DFEAT + gl * 8];
#pragma unroll
                for (int j = 0; j < 8; ++j) a[j] += bf2f(v0[j]) + bf2f(v1[j]);
            }
            if (e < end) {
                int c0 = p.scol[e];
                ushort8v v0 = *(const ushort8v*)&hcur[(size_t)c0 * DFEAT + gl * 8];
#pragma unroll
                for (int j = 0; j < 8; ++j) a[j] += bf2f(v0[j]);
            }
            ushort8v o;
#pragma unroll
            for (int j = 0; j < 8; ++j) o[j] = f2bf(a[j]);
            *(ushort8v*)&p.Ab[(size_t)node * DFEAT + gl * 8] = o;
        }
        grid.sync();

        // --- fused GEMM: H' = relu(H@W1^T + A@W2^T) ---
        {
            const ushort* W1b = p.Wb + (size_t)(2 * l) * DFEAT * DFEAT;
            const ushort* W2b = p.Wb + (size_t)(2 * l + 1) * DFEAT * DFEAT;
            bf16x8 w1[4][4], w2[4][4];
#pragma unroll
            for (int ot = 0; ot < 4; ++ot)
#pragma unroll
                for (int ks = 0; ks < 4; ++ks) {
                    int orow = half * 64 + ot * 16 + l15;
                    w1[ot][ks] = *(const bf16x8*)&W1b[orow * DFEAT + ks * 32 + lhi * 8];
                    w2[ot][ks] = *(const bf16x8*)&W2b[orow * DFEAT + ks * 32 + lhi * 8];
                }
            const int ntiles = NNODES / 16;            // 6250
            for (int tt = team; tt < ntiles; tt += NWAVES / 2) {
                size_t rowOff = (size_t)(tt * 16 + l15) * DFEAT;
                bf16x8 hfr[4], afr[4];
#pragma unroll
                for (int ks = 0; ks < 4; ++ks) {
                    hfr[ks] = *(const bf16x8*)&hcur[rowOff + ks * 32 + lhi * 8];
                    afr[ks] = *(const bf16x8*)&p.Ab[rowOff + ks * 32 + lhi * 8];
                }
#pragma unroll
                for (int ot = 0; ot < 4; ++ot) {
                    f32x4 acc = {};
#pragma unroll
                    for (int ks = 0; ks < 4; ++ks)
                        acc = __builtin_amdgcn_mfma_f32_16x16x32_bf16(w1[ot][ks], hfr[ks], acc, 0, 0, 0);
#pragma unroll
                    for (int ks = 0; ks < 4; ++ks)
                        acc = __builtin_amdgcn_mfma_f32_16x16x32_bf16(w2[ot][ks], afr[ks], acc, 0, 0, 0);
                    ushort4 pk;
                    pk.x = f2bf(fmaxf(acc.x, 0.f));
                    pk.y = f2bf(fmaxf(acc.y, 0.f));
                    pk.z = f2bf(fmaxf(acc.z, 0.f));
                    pk.w = f2bf(fmaxf(acc.w, 0.f));
                    *(ushort4*)&hnext[rowOff + half * 64 + ot * 16 + lhi * 4] = pk;
                }
            }
        }
        grid.sync();
        const ushort* tmp = hcur; hcur = hnext; hnext = (ushort*)tmp;
    }

    // ---------------- P5: pool partial (run-accumulate, sorted batch) -----
    {
        const int chunk = (NNODES + NWAVES - 1) / NWAVES;      // 49
        int base = gw * chunk;
        if (base < NNODES) {
            int end = min(base + chunk, NNODES);
            const uint* Hp = (const uint*)hcur + lane;
            float ax = 0.f, ay = 0.f;
            int gprev = p.batch[base];
            for (int n = base; n < end; ++n) {
                int g = p.batch[n];
                if (g != gprev) {
                    atomicAdd(&p.gsum[gprev * DFEAT + lane * 2], ax);
                    atomicAdd(&p.gsum[gprev * DFEAT + lane * 2 + 1], ay);
                    ax = 0.f; ay = 0.f; gprev = g;
                }
                uint v = Hp[(size_t)n * 64];
                ax += __builtin_bit_cast(float, v << 16);
                ay += __builtin_bit_cast(float, v & 0xffff0000u);
            }
            atomicAdd(&p.gsum[gprev * DFEAT + lane * 2], ax);
            atomicAdd(&p.gsum[gprev * DFEAT + lane * 2 + 1], ay);
        }
    }
    grid.sync();

    // ---------------- P6: classify (block b = graph b) ---------------------
    {
        int g = b;
        int f = t;
        if (f < 2) {
            int target = g + f;
            int lo = 0, hi = NNODES;
            while (lo < hi) {
                int mid = (lo + hi) >> 1;
                if (p.batch[mid] < target) lo = mid + 1; else hi = mid;
            }
            bounds[f] = lo;
        }
        __syncthreads();
        float pooled = 0.f;
        if (f < DFEAT) {
            float cnt = (float)(bounds[1] - bounds[0]);
            pooled = p.gsum[g * DFEAT + f] / fmaxf(cnt, 1.0f);
        }
        for (int o = 0; o < DOUTC; ++o) {
            if (f < DFEAT) red[f] = pooled * p.Wc[o * DFEAT + f];
            __syncthreads();
            for (int off = 64; off > 0; off >>= 1) {
                if (f < off) red[f] += red[f + off];
                __syncthreads();
            }
            if (f == 0) p.out[g * DOUTC + o] = red[0] + p.bc[o];
            __syncthreads();
        }
    }
}

// ---------------------------------------------------------------------------
extern "C" void kernel_launch(void* const* d_in, const int* in_sizes, int n_in,
                              void* d_out, int out_size, void* d_ws, size_t ws_size,
                              hipStream_t stream) {
    Params p;
    p.x     = (const float*)d_in[0];
    const int* ei = (const int*)d_in[1];
    p.rows  = ei;                  // edge_index[0] = dst (segment)
    p.cols  = ei + NEDGES;         // edge_index[1] = src (gather)
    p.batch = (const int*)d_in[2];
    p.W[0]  = (const float*)d_in[3];
    p.W[1]  = (const float*)d_in[4];
    p.W[2]  = (const float*)d_in[5];
    p.W[3]  = (const float*)d_in[6];
    p.W[4]  = (const float*)d_in[7];
    p.W[5]  = (const float*)d_in[8];
    p.Wc    = (const float*)d_in[9];
    p.bc    = (const float*)d_in[10];
    p.out   = (float*)d_out;

    char* ws = (char*)d_ws;
    p.Hb   = (ushort*)ws;  ws += (size_t)NNODES * DFEAT * sizeof(ushort);
    p.Hc   = (ushort*)ws;  ws += (size_t)NNODES * DFEAT * sizeof(ushort);
    p.Ab   = (ushort*)ws;  ws += (size_t)NNODES * DFEAT * sizeof(ushort);
    p.Wb   = (ushort*)ws;  ws += (size_t)6 * DFEAT * DFEAT * sizeof(ushort);
    p.gsum = (float*)ws;   ws += (size_t)NGRAPH * DFEAT * sizeof(float);
    p.deg  = (int*)ws;     ws += (size_t)NNODES * sizeof(int);
    p.offs = (int*)ws;     ws += (size_t)(NNODES + 1) * sizeof(int);
    p.cursor = (int*)ws;   ws += (size_t)NNODES * sizeof(int);
    p.scol = (int*)ws;     ws += (size_t)NEDGES * sizeof(int);
    p.bsum = (int*)ws;     ws += 128 * sizeof(int);
    p.bbase = (int*)ws;    ws += 128 * sizeof(int);

    void* args[] = { &p };
    hipLaunchCooperativeKernel((const void*)gnn_mega, dim3(NBLK), dim3(NTHR),
                               args, 0, stream);
}